// Round 4
// baseline (93.859 us; speedup 1.0000x reference)
//
#include <hip/hip_runtime.h>

// ES_Normalize: y[b,i,d] = a*y[b,i-1,d] + (1-a)*x[b,i,d], y[b,0,d] = x[b,0,d]
// Outputs (concatenated flat): y [B,L,D] fp32, then y[:,L-1,:] [B,D] fp32.
//
// Chunked-scan with decay-halo: ALPHA=0.3 decays the initial-carry error by
// 0.3^H; H=10 -> 5.9e-6, four orders below the 8.25e-2 threshold (chunk 0
// exact). Ladder: S=128 (2 w/SIMD) 114us -> S=64 (4 w/SIMD) 89.6us; this
// round S=32 -> 64 chunks, 8192 waves (8/SIMD, 32/CU). Halo re-reads are
// the previous chunk's main rows -> L2/L3 hits, not HBM. nt stores for y.

typedef float f32x4 __attribute__((ext_vector_type(4)));

constexpr int B = 64;
constexpr int L = 2048;
constexpr int D = 512;
constexpr int D4 = D / 4;       // 128 float4 columns per row
constexpr int S = 32;           // chunk length along L
constexpr int NCHUNK = L / S;   // 64
constexpr int H = 10;           // halo warm-up rows (0.3^10 ~ 5.9e-6)

__global__ __launch_bounds__(256) void es_scan_kernel(
    const float* __restrict__ x, float* __restrict__ y,
    float* __restrict__ ylast) {
  const float a = 0.3f;
  const float oma = 1.0f - a;

  const int t = blockIdx.x * blockDim.x + threadIdx.x;
  const int d4 = t % D4;
  const int rest = t / D4;
  const int chunk = rest % NCHUNK;
  const int b = rest / NCHUNK;

  const int i0 = chunk * S;
  const int start = (chunk == 0) ? 0 : (i0 - H);

  // base element offset of (b, row=0, col=d4*4)
  const size_t base = (size_t)b * L * D + (size_t)d4 * 4;

  // init carry from x[start] (exact for chunk 0, approx otherwise)
  f32x4 yv = *reinterpret_cast<const f32x4*>(x + base + (size_t)start * D);
  if (chunk == 0) {
    __builtin_nontemporal_store(yv, reinterpret_cast<f32x4*>(y + base));
  }

  // halo warm-up: no stores (chunk 0 skips: start==i0 there)
  #pragma unroll
  for (int k = 1; k <= H; ++k) {
    const int i = start + k;
    if (i < i0) {
      const f32x4 xv =
          *reinterpret_cast<const f32x4*>(x + base + (size_t)i * D);
      yv = a * yv + oma * xv;  // vector fma
    }
  }

  // main chunk: compute + store
  const int istart = (chunk == 0) ? 1 : i0;
  const int iend = i0 + S;
  #pragma unroll 4
  for (int i = istart; i < iend; ++i) {
    const f32x4 xv = *reinterpret_cast<const f32x4*>(x + base + (size_t)i * D);
    yv = a * yv + oma * xv;
    __builtin_nontemporal_store(
        yv, reinterpret_cast<f32x4*>(y + base + (size_t)i * D));
  }

  // last-row output
  if (iend == L) {
    __builtin_nontemporal_store(
        yv, reinterpret_cast<f32x4*>(ylast + (size_t)b * D + (size_t)d4 * 4));
  }
}

extern "C" void kernel_launch(void* const* d_in, const int* in_sizes, int n_in,
                              void* d_out, int out_size, void* d_ws,
                              size_t ws_size, hipStream_t stream) {
  const float* x = (const float*)d_in[0];
  float* y = (float*)d_out;
  float* ylast = y + (size_t)B * L * D;

  const int total = B * NCHUNK * D4;  // 524288
  const int block = 256;
  const int grid = total / block;     // 2048
  es_scan_kernel<<<grid, block, 0, stream>>>(x, y, ylast);
}

// Round 5
// 90.055 us; speedup vs baseline: 1.0422x; 1.0422x over previous
//
#include <hip/hip_runtime.h>

// ES_Normalize: y[b,i,d] = a*y[b,i-1,d] + (1-a)*x[b,i,d], y[b,0,d] = x[b,0,d]
// Outputs (concatenated flat): y [B,L,D] fp32, then y[:,L-1,:] [B,D] fp32.
//
// Chunked-scan with decay-halo (0.3^11 ~ 2e-6 << 8.25e-2 threshold; chunk 0
// exact). Ladder: S=128 114us -> S=64 89.6us -> S=32 93.9us (halo overhead
// beat occupancy gain; reverted). This round keeps S=64 and restructures the
// inner loop into T=8 row bursts: 8 back-to-back loads (8 outstanding -> 2x
// MLP), 8 FMAs, 8 back-to-back nontemporal stores (read/write streams
// separated in time to cut HBM channel turnaround).

typedef float f32x4 __attribute__((ext_vector_type(4)));

constexpr int B = 64;
constexpr int L = 2048;
constexpr int D = 512;
constexpr int D4 = D / 4;       // 128 float4 columns per row
constexpr int S = 64;           // chunk length along L
constexpr int NCHUNK = L / S;   // 32
constexpr int H = 12;           // halo rows (init + 11 warm-up FMAs)
constexpr int T = 8;            // burst length (rows per load/store burst)

__global__ __launch_bounds__(256) void es_scan_kernel(
    const float* __restrict__ x, float* __restrict__ y,
    float* __restrict__ ylast) {
  const float a = 0.3f;
  const float oma = 1.0f - a;

  const int t = blockIdx.x * blockDim.x + threadIdx.x;
  const int d4 = t % D4;
  const int rest = t / D4;
  const int chunk = rest % NCHUNK;   // wave-uniform (wave spans 64 d4 cols)
  const int b = rest / NCHUNK;

  const int i0 = chunk * S;
  const size_t base = (size_t)b * L * D + (size_t)d4 * 4;
  const float* xp = x + base;
  float* yp = y + base;

  f32x4 yv;
  const bool c0 = (chunk == 0);
  if (!c0) {
    // halo warm-up: init at x[i0-H], then H-1 FMAs (no stores)
    const int start = i0 - H;
    yv = *reinterpret_cast<const f32x4*>(xp + (size_t)start * D);
    #pragma unroll
    for (int k = 1; k < H; ++k) {
      const f32x4 xv =
          *reinterpret_cast<const f32x4*>(xp + (size_t)(start + k) * D);
      yv = a * yv + oma * xv;
    }
  }

  // main chunk: bursts of T rows (load burst / FMA chain / store burst)
  #pragma unroll 1
  for (int blk = 0; blk < S; blk += T) {
    f32x4 xv[T];
    #pragma unroll
    for (int j = 0; j < T; ++j) {
      xv[j] =
          *reinterpret_cast<const f32x4*>(xp + (size_t)(i0 + blk + j) * D);
    }
    f32x4 ov[T];
    #pragma unroll
    for (int j = 0; j < T; ++j) {
      if (j == 0 && c0 && blk == 0) {
        yv = xv[0];  // y[0] = x[0]
      } else {
        yv = a * yv + oma * xv[j];
      }
      ov[j] = yv;
    }
    #pragma unroll
    for (int j = 0; j < T; ++j) {
      __builtin_nontemporal_store(
          ov[j], reinterpret_cast<f32x4*>(yp + (size_t)(i0 + blk + j) * D));
    }
  }

  // last-row output
  if (i0 + S == L) {
    __builtin_nontemporal_store(
        yv, reinterpret_cast<f32x4*>(ylast + (size_t)b * D + (size_t)d4 * 4));
  }
}

extern "C" void kernel_launch(void* const* d_in, const int* in_sizes, int n_in,
                              void* d_out, int out_size, void* d_ws,
                              size_t ws_size, hipStream_t stream) {
  const float* x = (const float*)d_in[0];
  float* y = (float*)d_out;
  float* ylast = y + (size_t)B * L * D;

  const int total = B * NCHUNK * D4;  // 262144
  const int block = 256;
  const int grid = total / block;     // 1024
  es_scan_kernel<<<grid, block, 0, stream>>>(x, y, ylast);
}

// Round 6
// 88.307 us; speedup vs baseline: 1.0629x; 1.0198x over previous
//
#include <hip/hip_runtime.h>

// ES_Normalize: y[b,i,d] = a*y[b,i-1,d] + (1-a)*x[b,i,d], y[b,0,d] = x[b,0,d]
// Outputs (concatenated flat): y [B,L,D] fp32, then y[:,L-1,:] [B,D] fp32.
//
// Chunked-scan with decay-halo (0.3^11 ~ 1.8e-6 << 8.25e-2; chunk 0 exact).
// Ladder: S=128/f4 114us -> S=64/f4 89.6us -> S=32/f4 93.9us (halo beat
// occupancy) -> T=8 bursts neutral. This round: S=64 but float2-wide threads
// -> 2x threads (8 waves/SIMD, ~64% occupancy) at IDENTICAL halo traffic
// (threads x2, halo bytes/thread /2). Isolates the occupancy lever that
// round 4 confounded with halo overhead.

typedef float f32x2 __attribute__((ext_vector_type(2)));

constexpr int B = 64;
constexpr int L = 2048;
constexpr int D = 512;
constexpr int D2 = D / 2;       // 256 float2 columns per row
constexpr int S = 64;           // chunk length along L
constexpr int NCHUNK = L / S;   // 32
constexpr int H = 12;           // halo rows (init + 11 warm-up FMAs)

__global__ __launch_bounds__(256) void es_scan_kernel(
    const float* __restrict__ x, float* __restrict__ y,
    float* __restrict__ ylast) {
  const float a = 0.3f;
  const float oma = 1.0f - a;

  const int t = blockIdx.x * blockDim.x + threadIdx.x;
  const int d2 = t % D2;
  const int rest = t / D2;
  const int chunk = rest % NCHUNK;
  const int b = rest / NCHUNK;

  const int i0 = chunk * S;
  const size_t base = (size_t)b * L * D + (size_t)d2 * 2;
  const float* xp = x + base;
  float* yp = y + base;

  f32x2 yv;
  const bool c0 = (chunk == 0);
  if (!c0) {
    // halo warm-up: init at x[i0-H], then H-1 FMAs (no stores)
    const int start = i0 - H;
    yv = *reinterpret_cast<const f32x2*>(xp + (size_t)start * D);
    #pragma unroll
    for (int k = 1; k < H; ++k) {
      const f32x2 xv =
          *reinterpret_cast<const f32x2*>(xp + (size_t)(start + k) * D);
      yv = a * yv + oma * xv;
    }
  } else {
    yv = *reinterpret_cast<const f32x2*>(xp);  // y[0] = x[0]
    __builtin_nontemporal_store(yv, reinterpret_cast<f32x2*>(yp));
  }

  // main chunk: compute + store
  const int istart = c0 ? 1 : i0;
  const int iend = i0 + S;
  #pragma unroll 4
  for (int i = istart; i < iend; ++i) {
    const f32x2 xv = *reinterpret_cast<const f32x2*>(xp + (size_t)i * D);
    yv = a * yv + oma * xv;
    __builtin_nontemporal_store(
        yv, reinterpret_cast<f32x2*>(yp + (size_t)i * D));
  }

  // last-row output
  if (iend == L) {
    __builtin_nontemporal_store(
        yv, reinterpret_cast<f32x2*>(ylast + (size_t)b * D + (size_t)d2 * 2));
  }
}

extern "C" void kernel_launch(void* const* d_in, const int* in_sizes, int n_in,
                              void* d_out, int out_size, void* d_ws,
                              size_t ws_size, hipStream_t stream) {
  const float* x = (const float*)d_in[0];
  float* y = (float*)d_out;
  float* ylast = y + (size_t)B * L * D;

  const int total = B * NCHUNK * D2;  // 524288
  const int block = 256;
  const int grid = total / block;     // 2048
  es_scan_kernel<<<grid, block, 0, stream>>>(x, y, ylast);
}

// Round 7
// 87.788 us; speedup vs baseline: 1.0692x; 1.0059x over previous
//
#include <hip/hip_runtime.h>

// ES_Normalize: y[b,i,d] = a*y[b,i-1,d] + (1-a)*x[b,i,d], y[b,0,d] = x[b,0,d]
// Outputs (concatenated flat): y [B,L,D] fp32, then y[:,L-1,:] [B,D] fp32.
//
// Chunked-scan with decay-halo (0.3^11 ~ 1.8e-6 << 8.25e-2; chunk 0 exact).
// Ladder: S=128/f4 114us -> S=64/f4 89.6 -> S=32 93.9 (halo cost) -> T=8
// bursts 90.1 -> f32x2 88.3. All TLP/MLP levers neutral => suspect gfx9
// vmcnt store-gating: vmcnt counts loads AND stores in issue order, so a
// load-wait behind older-issued stores also waits for HBM write completion.
// This round: explicit software pipeline — issue loads(burst k+1) BEFORE
// stores(burst k), so load-waits leave stores outstanding (vmcnt(16) skips
// the 8 newer stores + 8 newer loads). nt stores keep y out of L3 so x
// stays L3-resident across replays (FETCH 155MB < 268MB).

typedef float f32x2 __attribute__((ext_vector_type(2)));

constexpr int B = 64;
constexpr int L = 2048;
constexpr int D = 512;
constexpr int D2 = D / 2;       // 256 float2 columns per row
constexpr int S = 64;           // chunk length along L
constexpr int NCHUNK = L / S;   // 32
constexpr int H = 12;           // halo rows (init + 11 warm-up FMAs)
constexpr int T = 8;            // burst length
constexpr int NB = S / T;       // 8 bursts per chunk

__global__ __launch_bounds__(256) void es_scan_kernel(
    const float* __restrict__ x, float* __restrict__ y,
    float* __restrict__ ylast) {
  const float a = 0.3f;
  const float oma = 1.0f - a;

  const int t = blockIdx.x * blockDim.x + threadIdx.x;
  const int d2 = t % D2;
  const int rest = t / D2;
  const int chunk = rest % NCHUNK;
  const int b = rest / NCHUNK;

  const int i0 = chunk * S;
  const size_t base = (size_t)b * L * D + (size_t)d2 * 2;
  const float* xp = x + base + (size_t)i0 * D;  // chunk start
  float* yp = y + base + (size_t)i0 * D;

  f32x2 yv;
  const bool c0 = (chunk == 0);
  if (!c0) {
    // halo warm-up: 12 parallel loads, then serial FMA chain (no stores)
    const float* hp = xp - (size_t)H * D;
    f32x2 hv[H];
    #pragma unroll
    for (int k = 0; k < H; ++k) {
      hv[k] = *reinterpret_cast<const f32x2*>(hp + (size_t)k * D);
    }
    yv = hv[0];
    #pragma unroll
    for (int k = 1; k < H; ++k) {
      yv = a * yv + oma * hv[k];
    }
  }

  // software-pipelined main loop: loads(k+1) issued BEFORE stores(k)
  f32x2 cur[T], nxt[T];
  #pragma unroll
  for (int j = 0; j < T; ++j) {
    cur[j] = *reinterpret_cast<const f32x2*>(xp + (size_t)j * D);
  }

  #pragma unroll
  for (int blk = 0; blk < NB; ++blk) {
    if (blk + 1 < NB) {
      #pragma unroll
      for (int j = 0; j < T; ++j) {
        nxt[j] = *reinterpret_cast<const f32x2*>(
            xp + (size_t)((blk + 1) * T + j) * D);
      }
    }
    f32x2 ov[T];
    #pragma unroll
    for (int j = 0; j < T; ++j) {
      if (c0 && blk == 0 && j == 0) {
        yv = cur[0];  // y[0] = x[0]
      } else {
        yv = a * yv + oma * cur[j];
      }
      ov[j] = yv;
    }
    #pragma unroll
    for (int j = 0; j < T; ++j) {
      __builtin_nontemporal_store(
          ov[j], reinterpret_cast<f32x2*>(yp + (size_t)(blk * T + j) * D));
    }
    #pragma unroll
    for (int j = 0; j < T; ++j) cur[j] = nxt[j];
  }

  // last-row output
  if (i0 + S == L) {
    __builtin_nontemporal_store(
        yv, reinterpret_cast<f32x2*>(ylast + (size_t)b * D + (size_t)d2 * 2));
  }
}

extern "C" void kernel_launch(void* const* d_in, const int* in_sizes, int n_in,
                              void* d_out, int out_size, void* d_ws,
                              size_t ws_size, hipStream_t stream) {
  const float* x = (const float*)d_in[0];
  float* y = (float*)d_out;
  float* ylast = y + (size_t)B * L * D;

  const int total = B * NCHUNK * D2;  // 524288
  const int block = 256;
  const int grid = total / block;     // 2048
  es_scan_kernel<<<grid, block, 0, stream>>>(x, y, ylast);
}